// Round 1
// baseline (241.901 us; speedup 1.0000x reference)
//
#include <hip/hip_runtime.h>
#include <math.h>

#define DD   128      // embed dim
#define ROWS 64       // rows per block (lane == row)
#define NW   8        // waves per block
#define TPB  (NW*64)  // 512 threads
#define JPW  16       // output columns per wave (128 / 8)
#define MAXBLK 8192

// cross-kernel scalars / partials (static device memory: no ws needed, deterministic)
__device__ float g_m;
__device__ float g_invZ;
__device__ float g_pm[MAXBLK];
__device__ float g_ps[MAXBLK];

__global__ __launch_bounds__(TPB, 8)
void k_mlp(const float* __restrict__ node1,
           const float* __restrict__ urep,
           const float* __restrict__ W1, const float* __restrict__ b1,
           const float* __restrict__ W2, const float* __restrict__ b2,
           const float* __restrict__ W3, const float* __restrict__ b3,
           float* __restrict__ out, int n)
{
    __shared__ float Xs[ROWS * 129];      // 33 KB, pad 129 -> (lane+k)%32 banks, 2-way free
    const int tid  = threadIdx.x;
    const int lane = tid & 63;
    const int w    = __builtin_amdgcn_readfirstlane(tid >> 6);  // force wave-uniform -> SGPR
    const int c0   = w * JPW;
    const int r0   = blockIdx.x * ROWS;

    // ---- stage X tile: 64 rows x 128 f32, fully coalesced float4 ----
    #pragma unroll
    for (int i = 0; i < 4; ++i) {
        int f   = tid + i * TPB;          // float4 index 0..2047 (= row*32 + kq)
        int row = f >> 5;
        int kq  = f & 31;
        if (r0 + row < n) {
            float4 v = reinterpret_cast<const float4*>(node1)[r0 * 32 + f];
            float* dst = &Xs[row * 129 + kq * 4];
            dst[0] = v.x; dst[1] = v.y; dst[2] = v.z; dst[3] = v.w;
        }
    }

    // ---- fold u_rep half of layer1 into bias (per-wave, tiny) ----
    float b1p[JPW];
    {
        float u0 = urep[lane];
        float u1 = urep[64 + lane];
        #pragma unroll
        for (int jj = 0; jj < JPW; ++jj) {
            const float* wr = W1 + (size_t)(c0 + jj) * (2 * DD) + DD;
            float p = wr[lane] * u0 + wr[64 + lane] * u1;
            #pragma unroll
            for (int off = 32; off > 0; off >>= 1) p += __shfl_xor(p, off);
            b1p[jj] = p + b1[c0 + jj];
        }
    }
    __syncthreads();

    float acc[JPW];

    // ---- layer 1: h1[c] = relu( x . W1[c,0:128] + b1'[c] ), W via scalar loads ----
    #pragma unroll
    for (int jj = 0; jj < JPW; ++jj) acc[jj] = b1p[jj];
    {
        const float* xr    = &Xs[lane * 129];
        const float* wbase = W1 + (size_t)c0 * (2 * DD);
        #pragma unroll 4
        for (int k = 0; k < DD; ++k) {
            float xk = xr[k];
            #pragma unroll
            for (int jj = 0; jj < JPW; ++jj)
                acc[jj] = fmaf(xk, wbase[jj * (2 * DD) + k], acc[jj]);
        }
    }
    __syncthreads();
    #pragma unroll
    for (int jj = 0; jj < JPW; ++jj)
        Xs[lane * 129 + c0 + jj] = fmaxf(acc[jj], 0.0f);   // h1 overwrites x
    __syncthreads();

    // ---- layer 2 ----
    #pragma unroll
    for (int jj = 0; jj < JPW; ++jj) acc[jj] = b2[c0 + jj];
    {
        const float* xr    = &Xs[lane * 129];
        const float* wbase = W2 + (size_t)c0 * DD;
        #pragma unroll 4
        for (int k = 0; k < DD; ++k) {
            float xk = xr[k];
            #pragma unroll
            for (int jj = 0; jj < JPW; ++jj)
                acc[jj] = fmaf(xk, wbase[jj * DD + k], acc[jj]);
        }
    }
    __syncthreads();

    // ---- layer 3 partial: relu(h2) . W3 slice ----
    float p3 = 0.0f;
    #pragma unroll
    for (int jj = 0; jj < JPW; ++jj)
        p3 = fmaf(fmaxf(acc[jj], 0.0f), W3[c0 + jj], p3);
    Xs[lane * 129 + w] = p3;
    __syncthreads();

    if (w == 0) {
        float s = b3[0];
        #pragma unroll
        for (int ww = 0; ww < NW; ++ww) s += Xs[lane * 129 + ww];
        bool valid = (r0 + lane) < n;
        if (valid) out[r0 + lane] = s;

        // per-block online-softmax stats (deterministic, no atomics)
        float sv = valid ? s : -3.0e38f;
        float Lm = sv;
        #pragma unroll
        for (int off = 32; off > 0; off >>= 1) Lm = fmaxf(Lm, __shfl_xor(Lm, off));
        float e = valid ? expf(s - Lm) : 0.0f;
        #pragma unroll
        for (int off = 32; off > 0; off >>= 1) e += __shfl_xor(e, off);
        if (lane == 0) { g_pm[blockIdx.x] = Lm; g_ps[blockIdx.x] = e; }
    }
}

__global__ __launch_bounds__(1024)
void k_combine(int nblk)
{
    __shared__ float red[17];
    const int tid = threadIdx.x, lane = tid & 63, wv = tid >> 6;

    float m = -3.0e38f;
    for (int i = tid; i < nblk; i += 1024) m = fmaxf(m, g_pm[i]);
    #pragma unroll
    for (int off = 32; off > 0; off >>= 1) m = fmaxf(m, __shfl_xor(m, off));
    if (lane == 0) red[wv] = m;
    __syncthreads();
    if (tid < 64) {
        float v = (lane < 16) ? red[lane] : -3.0e38f;
        #pragma unroll
        for (int off = 32; off > 0; off >>= 1) v = fmaxf(v, __shfl_xor(v, off));
        if (lane == 0) red[16] = v;
    }
    __syncthreads();
    m = red[16];

    float z = 0.0f;
    for (int i = tid; i < nblk; i += 1024) z += g_ps[i] * expf(g_pm[i] - m);
    #pragma unroll
    for (int off = 32; off > 0; off >>= 1) z += __shfl_xor(z, off);
    __syncthreads();
    if (lane == 0) red[wv] = z;
    __syncthreads();
    if (tid < 64) {
        float v = (lane < 16) ? red[lane] : 0.0f;
        #pragma unroll
        for (int off = 32; off > 0; off >>= 1) v += __shfl_xor(v, off);
        if (lane == 0) { g_m = m; g_invZ = 1.0f / v; }
    }
}

__global__ __launch_bounds__(256)
void k_norm(float* __restrict__ s, int n)
{
    const int i = blockIdx.x * 256 + threadIdx.x;
    const float m = g_m, r = g_invZ;
    const int n4 = n >> 2;
    if (i < n4) {
        float4 v = reinterpret_cast<float4*>(s)[i];
        v.x = expf(v.x - m) * r;
        v.y = expf(v.y - m) * r;
        v.z = expf(v.z - m) * r;
        v.w = expf(v.w - m) * r;
        reinterpret_cast<float4*>(s)[i] = v;
    }
    const int rem = n - (n4 << 2);
    if (i < rem) {
        int t = (n4 << 2) + i;
        s[t] = expf(s[t] - m) * r;
    }
}

extern "C" void kernel_launch(void* const* d_in, const int* in_sizes, int n_in,
                              void* d_out, int out_size, void* d_ws, size_t ws_size,
                              hipStream_t stream)
{
    const float* node1 = (const float*)d_in[0];
    const float* urep  = (const float*)d_in[1];
    const float* W1    = (const float*)d_in[3];
    const float* b1    = (const float*)d_in[4];
    const float* W2    = (const float*)d_in[5];
    const float* b2    = (const float*)d_in[6];
    const float* W3    = (const float*)d_in[7];
    const float* b3    = (const float*)d_in[8];
    float* out = (float*)d_out;

    const int n    = in_sizes[0] / DD;            // 200000
    const int nblk = (n + ROWS - 1) / ROWS;       // 3125 (fits MAXBLK)

    k_mlp<<<dim3(nblk), dim3(TPB), 0, stream>>>(node1, urep, W1, b1, W2, b2, W3, b3, out, n);
    k_combine<<<dim3(1), dim3(1024), 0, stream>>>(nblk);

    const int n4  = n >> 2;
    const int nb3 = (n4 + 255) / 256 > 0 ? (n4 + 255) / 256 : 1;
    k_norm<<<dim3(nb3), dim3(256), 0, stream>>>(out, n);
}

// Round 2
// 93.524 us; speedup vs baseline: 2.5865x; 2.5865x over previous
//
#include <hip/hip_runtime.h>
#include <hip/hip_bf16.h>
#include <math.h>

#define DD     128
#define BROWS  64          // rows per block
#define NWAVE  2
#define TPB    (NWAVE*64)  // 128 threads
#define WROWS  32          // rows per wave
#define XSTR   136         // bf16 elements per LDS row (272B, 16B-aligned, bank-uniform)
#define MAXBLK 8192

typedef __attribute__((ext_vector_type(8))) short bf16x8;
typedef __attribute__((ext_vector_type(4))) float f32x4;

// static device scratch (no ws dependency, rewritten every launch -> deterministic)
__device__ __align__(16) unsigned short g_wfrag[2*2*4*8*64*8]; // [L][T][s][mt][lane][8] = 128KB
__device__ __align__(16) float g_b1p[DD];
__device__ float g_m, g_invZ;
__device__ float g_pm[MAXBLK], g_ps[MAXBLK];

__device__ __forceinline__ unsigned short f2b(float x){
    union { __hip_bfloat16 b; unsigned short u; } c;
    c.b = __float2bfloat16(x);
    return c.u;
}
__device__ __forceinline__ float b2f(unsigned short u){
    union { __hip_bfloat16 b; unsigned short u; } c;
    c.u = u;
    return __bfloat162float(c.b);
}

// ---- prep: split W1(:, 0:128) and W2 into bf16 hi/lo, laid out in MFMA A-frag order ----
// A-frag for 16x16x32: lane l holds A[m = mt*16 + (l&15)][k = s*32 + (l>>4)*8 + r], r=0..7
__global__ __launch_bounds__(256)
void k_wprep(const float* __restrict__ W1, const float* __restrict__ W2)
{
    const int t    = blockIdx.x*256 + threadIdx.x;   // 0..8191
    const int lane = t & 63;
    const int mt   = (t>>6) & 7;
    const int s    = (t>>9) & 3;
    const int T    = (t>>11) & 1;                    // 0 = hi, 1 = lo
    const int L    = (t>>12) & 1;                    // 0 = layer1, 1 = layer2
    const int col  = mt*16 + (lane & 15);
    const int kb   = s*32 + ((lane>>4) << 3);
    const float* src = L ? (W2 + (size_t)col*128 + kb) : (W1 + (size_t)col*256 + kb);
    unsigned short o[8];
    #pragma unroll
    for (int r = 0; r < 8; ++r){
        float x = src[r];
        unsigned short h = f2b(x);
        o[r] = T ? f2b(x - b2f(h)) : h;
    }
    ushort4* dst = (ushort4*)&g_wfrag[(size_t)t * 8];
    dst[0] = *(ushort4*)&o[0];
    dst[1] = *(ushort4*)&o[4];
}

// ---- prep: fold u_rep half of layer1 into bias (exact fp32) ----
__global__ __launch_bounds__(128)
void k_b1p(const float* __restrict__ W1, const float* __restrict__ b1,
           const float* __restrict__ u)
{
    const int c = threadIdx.x;
    float a = b1[c];
    for (int j = 0; j < 128; ++j) a = fmaf(W1[(size_t)c*256 + 128 + j], u[j], a);
    g_b1p[c] = a;
}

// One layer: D[feature m][row n] = sum_k W[m][k]*x[n][k] + bias[m], split-bf16 3-term MFMA.
// TH = term base: layer1 -> 0, layer2 -> 2.
template<int TH>
__device__ __forceinline__ void mlp_layer(
    const unsigned short (&Xh)[BROWS*XSTR],
    const unsigned short (&Xl)[BROWS*XSTR],
    const float* __restrict__ bias,
    f32x4 (&acc)[8][2], int lane, int wrow0)
{
    #pragma unroll
    for (int mt = 0; mt < 8; ++mt){
        const float4 bv = *(const float4*)&bias[mt*16 + ((lane>>4)<<2)];
        f32x4 a; a[0] = bv.x; a[1] = bv.y; a[2] = bv.z; a[3] = bv.w;
        acc[mt][0] = a; acc[mt][1] = a;
    }
    const bf16x8* wf = (const bf16x8*)g_wfrag;
    #pragma unroll
    for (int s = 0; s < 4; ++s){
        bf16x8 Ah[8], Al[8];
        #pragma unroll
        for (int mt = 0; mt < 8; ++mt){
            Ah[mt] = wf[((((TH  )*4 + s)*8) + mt)*64 + lane];
            Al[mt] = wf[((((TH+1)*4 + s)*8) + mt)*64 + lane];
        }
        const int ra    = wrow0 + (lane & 15);
        const int koff  = s*32 + ((lane>>4) << 3);
        const bf16x8 Bh0 = *(const bf16x8*)&Xh[ra*XSTR + koff];
        const bf16x8 Bh1 = *(const bf16x8*)&Xh[(ra+16)*XSTR + koff];
        const bf16x8 Bl0 = *(const bf16x8*)&Xl[ra*XSTR + koff];
        const bf16x8 Bl1 = *(const bf16x8*)&Xl[(ra+16)*XSTR + koff];
        #pragma unroll
        for (int mt = 0; mt < 8; ++mt){
            acc[mt][0] = __builtin_amdgcn_mfma_f32_16x16x32_bf16(Ah[mt], Bh0, acc[mt][0], 0,0,0);
            acc[mt][1] = __builtin_amdgcn_mfma_f32_16x16x32_bf16(Ah[mt], Bh1, acc[mt][1], 0,0,0);
            acc[mt][0] = __builtin_amdgcn_mfma_f32_16x16x32_bf16(Ah[mt], Bl0, acc[mt][0], 0,0,0);
            acc[mt][1] = __builtin_amdgcn_mfma_f32_16x16x32_bf16(Ah[mt], Bl1, acc[mt][1], 0,0,0);
            acc[mt][0] = __builtin_amdgcn_mfma_f32_16x16x32_bf16(Al[mt], Bh0, acc[mt][0], 0,0,0);
            acc[mt][1] = __builtin_amdgcn_mfma_f32_16x16x32_bf16(Al[mt], Bh1, acc[mt][1], 0,0,0);
        }
    }
}

__global__ __launch_bounds__(TPB, 2)
void k_mlp(const float* __restrict__ node1,
           const float* __restrict__ b2,
           const float* __restrict__ W3,
           float* __restrict__ out, int n)
{
    __shared__ unsigned short Xh[BROWS*XSTR];   // 34816 B
    __shared__ unsigned short Xl[BROWS*XSTR];
    __shared__ float Ss[BROWS];
    const int tid   = threadIdx.x;
    const int lane  = tid & 63;
    const int w     = __builtin_amdgcn_readfirstlane(tid >> 6);
    const int wrow0 = w * WROWS;
    const int r0    = blockIdx.x * BROWS;

    // ---- stage x tile: 64 rows x 128 k, split to bf16 hi/lo in LDS ----
    #pragma unroll
    for (int i = 0; i < 16; ++i){
        int idx = i*TPB + tid;            // 0..2047 float4 slots (= row*32 + kq)
        int row = idx >> 5, kq = idx & 31;
        float4 v = {0.f, 0.f, 0.f, 0.f};
        if (r0 + row < n) v = reinterpret_cast<const float4*>(node1)[(size_t)(r0+row)*32 + kq];
        ushort4 hv, lv;
        hv.x = f2b(v.x); lv.x = f2b(v.x - b2f(hv.x));
        hv.y = f2b(v.y); lv.y = f2b(v.y - b2f(hv.y));
        hv.z = f2b(v.z); lv.z = f2b(v.z - b2f(hv.z));
        hv.w = f2b(v.w); lv.w = f2b(v.w - b2f(hv.w));
        *(ushort4*)&Xh[row*XSTR + kq*4] = hv;
        *(ushort4*)&Xl[row*XSTR + kq*4] = lv;
    }
    __syncthreads();

    f32x4 acc[8][2];

    // ---- layer 1 ----
    mlp_layer<0>(Xh, Xl, g_b1p, acc, lane, wrow0);

    // relu + bf16-split writeback (lane holds 4 consecutive features of one row -> b64 writes;
    // rows are wave-private so no barrier needed)
    #pragma unroll
    for (int mt = 0; mt < 8; ++mt){
        #pragma unroll
        for (int nt = 0; nt < 2; ++nt){
            const int row = wrow0 + nt*16 + (lane & 15);
            const int cb  = mt*16 + ((lane>>4)<<2);
            ushort4 hv, lv;
            float v;
            v = fmaxf(acc[mt][nt][0], 0.f); hv.x = f2b(v); lv.x = f2b(v - b2f(hv.x));
            v = fmaxf(acc[mt][nt][1], 0.f); hv.y = f2b(v); lv.y = f2b(v - b2f(hv.y));
            v = fmaxf(acc[mt][nt][2], 0.f); hv.z = f2b(v); lv.z = f2b(v - b2f(hv.z));
            v = fmaxf(acc[mt][nt][3], 0.f); hv.w = f2b(v); lv.w = f2b(v - b2f(hv.w));
            *(ushort4*)&Xh[row*XSTR + cb] = hv;
            *(ushort4*)&Xl[row*XSTR + cb] = lv;
        }
    }

    // ---- layer 2 ----
    mlp_layer<2>(Xh, Xl, b2, acc, lane, wrow0);

    // ---- layer 3: s[row] = sum_c relu(h2[c][row]) * W3[c]  (b3 cancels in softmax) ----
    float p3[2] = {0.f, 0.f};
    #pragma unroll
    for (int mt = 0; mt < 8; ++mt){
        const float4 wv = *(const float4*)&W3[mt*16 + ((lane>>4)<<2)];
        #pragma unroll
        for (int nt = 0; nt < 2; ++nt){
            p3[nt] = fmaf(fmaxf(acc[mt][nt][0], 0.f), wv.x, p3[nt]);
            p3[nt] = fmaf(fmaxf(acc[mt][nt][1], 0.f), wv.y, p3[nt]);
            p3[nt] = fmaf(fmaxf(acc[mt][nt][2], 0.f), wv.z, p3[nt]);
            p3[nt] = fmaf(fmaxf(acc[mt][nt][3], 0.f), wv.w, p3[nt]);
        }
    }
    #pragma unroll
    for (int nt = 0; nt < 2; ++nt){
        p3[nt] += __shfl_xor(p3[nt], 16);
        p3[nt] += __shfl_xor(p3[nt], 32);
    }
    if (lane < 16){
        Ss[wrow0 + lane]      = p3[0];
        Ss[wrow0 + 16 + lane] = p3[1];
    }
    __syncthreads();

    // ---- per-block online-softmax stats + raw score output (wave 0, lane = row) ----
    if (w == 0){
        const int ra = r0 + lane;
        const bool va = ra < n;
        const float s = Ss[lane];
        if (va) out[ra] = s;
        float m = va ? s : -3.0e38f;
        #pragma unroll
        for (int off = 32; off > 0; off >>= 1) m = fmaxf(m, __shfl_xor(m, off));
        float e = va ? expf(s - m) : 0.f;
        #pragma unroll
        for (int off = 32; off > 0; off >>= 1) e += __shfl_xor(e, off);
        if (lane == 0){ g_pm[blockIdx.x] = m; g_ps[blockIdx.x] = e; }
    }
}

__global__ __launch_bounds__(1024)
void k_combine(int nblk)
{
    __shared__ float red[17];
    const int tid = threadIdx.x, lane = tid & 63, wv = tid >> 6;

    float m = -3.0e38f;
    for (int i = tid; i < nblk; i += 1024) m = fmaxf(m, g_pm[i]);
    #pragma unroll
    for (int off = 32; off > 0; off >>= 1) m = fmaxf(m, __shfl_xor(m, off));
    if (lane == 0) red[wv] = m;
    __syncthreads();
    if (tid < 64){
        float v = (lane < 16) ? red[lane] : -3.0e38f;
        #pragma unroll
        for (int off = 32; off > 0; off >>= 1) v = fmaxf(v, __shfl_xor(v, off));
        if (lane == 0) red[16] = v;
    }
    __syncthreads();
    m = red[16];

    float z = 0.f;
    for (int i = tid; i < nblk; i += 1024) z += g_ps[i] * expf(g_pm[i] - m);
    #pragma unroll
    for (int off = 32; off > 0; off >>= 1) z += __shfl_xor(z, off);
    __syncthreads();
    if (lane == 0) red[wv] = z;
    __syncthreads();
    if (tid < 64){
        float v = (lane < 16) ? red[lane] : 0.f;
        #pragma unroll
        for (int off = 32; off > 0; off >>= 1) v += __shfl_xor(v, off);
        if (lane == 0){ g_m = m; g_invZ = 1.0f / v; }
    }
}

__global__ __launch_bounds__(256)
void k_norm(float* __restrict__ s, int n)
{
    const int i = blockIdx.x * 256 + threadIdx.x;
    const float m = g_m, r = g_invZ;
    const int n4 = n >> 2;
    if (i < n4){
        float4 v = reinterpret_cast<float4*>(s)[i];
        v.x = expf(v.x - m) * r;
        v.y = expf(v.y - m) * r;
        v.z = expf(v.z - m) * r;
        v.w = expf(v.w - m) * r;
        reinterpret_cast<float4*>(s)[i] = v;
    }
    const int rem = n - (n4 << 2);
    if (i < rem){
        int t = (n4 << 2) + i;
        s[t] = expf(s[t] - m) * r;
    }
}

extern "C" void kernel_launch(void* const* d_in, const int* in_sizes, int n_in,
                              void* d_out, int out_size, void* d_ws, size_t ws_size,
                              hipStream_t stream)
{
    const float* node1 = (const float*)d_in[0];
    const float* urep  = (const float*)d_in[1];
    const float* W1    = (const float*)d_in[3];
    const float* b1    = (const float*)d_in[4];
    const float* W2    = (const float*)d_in[5];
    const float* b2    = (const float*)d_in[6];
    const float* W3    = (const float*)d_in[7];
    float* out = (float*)d_out;

    const int n    = in_sizes[0] / DD;            // 200000
    const int nblk = (n + BROWS - 1) / BROWS;     // 3125

    k_wprep<<<dim3(32), dim3(256), 0, stream>>>(W1, W2);
    k_b1p<<<dim3(1), dim3(128), 0, stream>>>(W1, b1, urep);
    k_mlp<<<dim3(nblk), dim3(TPB), 0, stream>>>(node1, b2, W3, out, n);
    k_combine<<<dim3(1), dim3(1024), 0, stream>>>(nblk);

    const int n4  = n >> 2;
    const int nb3 = (n4 + 255) / 256 > 0 ? (n4 + 255) / 256 : 1;
    k_norm<<<dim3(nb3), dim3(256), 0, stream>>>(out, n);
}